// Round 9
// baseline (282.291 us; speedup 1.0000x reference)
//
#include <hip/hip_runtime.h>

#define N_NODES 100000
#define NBKT 782              // ceil(100000/128) buckets of 128 dst nodes
#define EPB 8192              // edges per partition block
#define SL_STRIDE 800000      // uints per y1 slice = N_NODES*8

typedef unsigned int uint;
typedef __attribute__((ext_vector_type(8))) short bf16x8;   // 8 bf16 (4 VGPRs)
typedef __attribute__((ext_vector_type(4))) float f32x4;    // MFMA acc / NT loads

union FragU { uint4 u; bf16x8 b; };

// ---------- bf16 helpers ------------------------------------------------------
__device__ __forceinline__ uint pack_bf16_2(float a, float b) {
    uint ua = __float_as_uint(a), ub = __float_as_uint(b);
    ua += 0x7fff + ((ua >> 16) & 1);           // RNE
    ub += 0x7fff + ((ub >> 16) & 1);
    return (ua >> 16) | (ub & 0xffff0000u);
}
__device__ __forceinline__ float bf_lo(uint u) { return __uint_as_float(u << 16); }
__device__ __forceinline__ float bf_hi(uint u) { return __uint_as_float(u & 0xffff0000u); }

// ---------- edge-index access (handles int32 or raw int64 little-endian) ----
__device__ __forceinline__ int edge_at(const int* __restrict__ ei, int idx, int is64) {
    return is64 ? ei[2 * idx] : ei[idx];
}

// per-block dtype probe: 1 if int64 little-endian layout (all odd words zero)
__device__ __forceinline__ int block_probe_is64(const int* __restrict__ ei, int* sh) {
    int t = threadIdx.x;
    if (t == 0) *sh = 0;
    __syncthreads();
    int any = 0;
    for (int j = t; j < 4096; j += blockDim.x) any |= ei[2 * j + 1];
    if (any) atomicOr(sh, 1);
    __syncthreads();
    return (*sh == 0);
}

// ---------- phase A1: bucket histogram -> private slab (no global atomics) ---
__global__ __launch_bounds__(256) void kA1(const int* __restrict__ ei, int E,
                                           int* __restrict__ slab) {
    __shared__ int h[NBKT];
    __shared__ int shp;
    int t = threadIdx.x;
    int is64 = block_probe_is64(ei, &shp);
    for (int i = t; i < NBKT; i += 256) h[i] = 0;
    __syncthreads();
    int base = blockIdx.x * EPB;
    int end = min(base + EPB, E);
    for (int e = base + t; e < end; e += 256) {
        int d = edge_at(ei, E + e, is64);
        atomicAdd(&h[d >> 7], 1);
    }
    __syncthreads();
    for (int i = t; i < NBKT; i += 256)
        slab[(size_t)blockIdx.x * NBKT + i] = h[i];
}

// ---------- phase A2: reduce slabs + exclusive scan (1 block) ----------------
__global__ __launch_bounds__(1024) void kA2(const int* __restrict__ slab, int PB,
                                            int* __restrict__ bkt_cnt,
                                            int* __restrict__ bkt_off,
                                            int* __restrict__ bkt_cursor) {
    __shared__ int s[1024];
    int t = threadIdx.x;
    int v = 0;
    if (t < NBKT)
        for (int b = 0; b < PB; ++b) v += slab[(size_t)b * NBKT + t];
    if (t < NBKT) bkt_cnt[t] = v;
    s[t] = v;
    __syncthreads();
    for (int d = 1; d < 1024; d <<= 1) {
        int y = (t >= d) ? s[t - d] : 0;
        __syncthreads();
        s[t] += y;
        __syncthreads();
    }
    if (t < NBKT) {
        int o = s[t] - v;                      // exclusive
        bkt_off[t] = o;
        bkt_cursor[t] = o;
    }
}

// ---------- phase A3: partition edges into bucket-major records --------------
__global__ __launch_bounds__(256) void kA3(const int* __restrict__ ei, int E,
                                           int* __restrict__ bkt_cursor,
                                           uint* __restrict__ bkt_data) {
    __shared__ int h[NBKT];
    __shared__ int base[NBKT];
    __shared__ int shp;
    int t = threadIdx.x;
    int is64 = block_probe_is64(ei, &shp);
    for (int i = t; i < NBKT; i += 256) h[i] = 0;
    __syncthreads();
    int lo = blockIdx.x * EPB;
    int end = min(lo + EPB, E);
    for (int e = lo + t; e < end; e += 256) {
        int d = edge_at(ei, E + e, is64);
        atomicAdd(&h[d >> 7], 1);
    }
    __syncthreads();
    for (int i = t; i < NBKT; i += 256) {
        int c = h[i];
        base[i] = c ? atomicAdd(&bkt_cursor[i], c) : 0;
    }
    __syncthreads();
    for (int i = t; i < NBKT; i += 256) h[i] = 0;   // reuse as local rank cursor
    __syncthreads();
    for (int e = lo + t; e < end; e += 256) {
        int d = edge_at(ei, E + e, is64);
        int s = edge_at(ei, e, is64);
        int b = d >> 7;
        int r = atomicAdd(&h[b], 1);
        bkt_data[base[b] + r] = ((uint)s << 7) | (uint)(d & 127);
    }
}

// ---------- phase B: per-bucket CSR build + degrees + dis + y2 zero ----------
__global__ __launch_bounds__(256) void kB(const uint* __restrict__ bkt_data,
                                          const int* __restrict__ bkt_off,
                                          const int* __restrict__ bkt_cnt,
                                          int* __restrict__ srcs,
                                          int* __restrict__ count,
                                          int* __restrict__ offs,
                                          float* __restrict__ dis,
                                          float* __restrict__ y2) {
    __shared__ int lc[128];    // local degree
    __shared__ int sc[128];    // inclusive scan
    __shared__ int lcur[128];  // local fill cursor
    int t = threadIdx.x;
    int b = blockIdx.x;
    // zero this block's slice of y2 (800000 floats over 782 blocks)
    {
        int zb = b * 1024;
        int ze = min(zb + 1024, N_NODES * 8);
        for (int i = zb + t; i < ze; i += 256) y2[i] = 0.0f;
    }
    if (t < 128) { lc[t] = 0; lcur[t] = 0; }
    __syncthreads();
    int start = bkt_off[b];
    int n = bkt_cnt[b];
    for (int i = t; i < n; i += 256)
        atomicAdd(&lc[bkt_data[start + i] & 127], 1);
    __syncthreads();
    if (t < 128) sc[t] = lc[t];
    __syncthreads();
    for (int d = 1; d < 128; d <<= 1) {
        int y = 0;
        if (t < 128 && t >= d) y = sc[t - d];
        __syncthreads();
        if (t < 128) sc[t] += y;
        __syncthreads();
    }
    if (t < 128) {
        int node = b * 128 + t;
        if (node < N_NODES) {
            int c = lc[t];
            count[node] = c;
            offs[node] = start + sc[t] - c;
            dis[node] = rsqrtf((float)c + 1.0f);
        }
    }
    __syncthreads();
    for (int i = t; i < n; i += 256) {
        uint rec = bkt_data[start + i];
        int dl = rec & 127;
        int r = atomicAdd(&lcur[dl], 1);
        srcs[start + (sc[dl] - lc[dl]) + r] = rec >> 7;
    }
}

// ---------- GEMM1 (MFMA bf16): y1s = bf16((x @ W1) * dis)  sliced layout -----
// Block = 64 rows, 4 waves x 16 rows. LDS: W1^T bf16, 16B-XOR swizzled.
// NT loads (ext-vector f32x4) for streaming x; NT stores for y1s.
__global__ __launch_bounds__(256) void k_gemm1(const float* __restrict__ x,
                                               const float* __restrict__ W,
                                               const float* __restrict__ dis,
                                               uint* __restrict__ y1s) {
    __shared__ uint4 WtA[2048];               // 32 KB
    char* wt = (char*)WtA;
    int t = threadIdx.x;

    const float4* W4 = (const float4*)W;
#pragma unroll
    for (int ii = 0; ii < 4; ++ii) {
        int tile = t + 256 * ii;              // 1024 (nq,kq) 4x4 tiles
        int nq = tile >> 5, kq = tile & 31;
        float4 r0 = W4[(4 * kq + 0) * 32 + nq];
        float4 r1 = W4[(4 * kq + 1) * 32 + nq];
        float4 r2 = W4[(4 * kq + 2) * 32 + nq];
        float4 r3 = W4[(4 * kq + 3) * 32 + nq];
        const float* p0 = (const float*)&r0;
        const float* p1 = (const float*)&r1;
        const float* p2 = (const float*)&r2;
        const float* p3 = (const float*)&r3;
#pragma unroll
        for (int cc = 0; cc < 4; ++cc) {
            int n = 4 * nq + cc;
            uint2 v;
            v.x = pack_bf16_2(p0[cc], p1[cc]);
            v.y = pack_bf16_2(p2[cc], p3[cc]);
            *(uint2*)(wt + n * 256 + (((kq >> 1) ^ (n & 7)) << 4) + ((kq & 1) << 3)) = v;
        }
    }
    __syncthreads();

    int w = t >> 6, lane = t & 63;
    int m = lane & 15, kg = lane >> 4;
    int row0 = blockIdx.x * 64 + 16 * w;

    int arow = row0 + m;
    bool av = arow < N_NODES;
    const f32x4* xr = (const f32x4*)(x + (size_t)arow * 128);
    f32x4 z4 = {0.f, 0.f, 0.f, 0.f};
    FragU af[4];
#pragma unroll
    for (int kf = 0; kf < 4; ++kf) {
        f32x4 g0 = av ? __builtin_nontemporal_load(&xr[8 * kf + 2 * kg])     : z4;
        f32x4 g1 = av ? __builtin_nontemporal_load(&xr[8 * kf + 2 * kg + 1]) : z4;
        af[kf].u.x = pack_bf16_2(g0[0], g0[1]);
        af[kf].u.y = pack_bf16_2(g0[2], g0[3]);
        af[kf].u.z = pack_bf16_2(g1[0], g1[1]);
        af[kf].u.w = pack_bf16_2(g1[2], g1[3]);
    }

    int crow = row0 + 4 * kg;
    float dd[4];
#pragma unroll
    for (int rr = 0; rr < 4; ++rr)
        dd[rr] = (crow + rr < N_NODES) ? dis[crow + rr] : 0.0f;

#pragma unroll
    for (int ct = 0; ct < 8; ++ct) {          // col-tile == slice
        f32x4 acc = {0.f, 0.f, 0.f, 0.f};
#pragma unroll
        for (int kf = 0; kf < 4; ++kf) {
            int n = 16 * ct + m;              // B col = lane&15
            bf16x8 bw = *(const bf16x8*)(wt + n * 256 + ((((kf << 2) | kg) ^ (n & 7)) << 4));
            acc = __builtin_amdgcn_mfma_f32_16x16x32_bf16(af[kf].b, bw, acc, 0, 0, 0);
        }
#pragma unroll
        for (int rr = 0; rr < 4; ++rr) {
            float v = acc[rr] * dd[rr];
            float p = __shfl_xor(v, 1, 64);   // partner col (odd)
            if (!(lane & 1)) {
                int grow = crow + rr;
                if (grow < N_NODES)
                    __builtin_nontemporal_store(pack_bf16_2(v, p),
                        &y1s[(size_t)ct * SL_STRIDE + grow * 8 + (m >> 1)]);
            }
        }
    }
}

// ---------- Aggregation 1 (sliced, XCD-local) fused with partial GEMM2 -------
// slice = blockIdx.x % 8 (round-robin XCD binding). 8-lane group per node.
// EDGE-PER-LANE: lane j handles edges i = j, j+8, ...; 2x dwordx4 per edge.
// Self-loop = virtual edge i==n. W2/b1 loads deferred to epilogue (VGPR).
__global__ __launch_bounds__(256) void k_agg1s(const uint* __restrict__ y1s,
                                               const int* __restrict__ srcs,
                                               const int* __restrict__ offs,
                                               const int* __restrict__ count,
                                               const float* __restrict__ dis,
                                               const float* __restrict__ b1,
                                               const float* __restrict__ W2,
                                               float* __restrict__ y2) {
    int t = threadIdx.x;
    int slice = blockIdx.x & 7;
    int nb = blockIdx.x >> 3;
    int g = t >> 3;                    // group 0..31
    int j = t & 7;                     // lane in group
    int d = nb * 32 + g;               // node (3125*32 == 100000)

    const uint4* ybase = (const uint4*)(y1s + (size_t)slice * SL_STRIDE);
    float acc[16];
#pragma unroll
    for (int c = 0; c < 16; ++c) acc[c] = 0.0f;

    int st = offs[d], n = count[d];
    for (int i = j; i <= n; i += 8) {            // i==n -> self-loop (one lane)
        int sk = d;
        if (i < n) sk = __builtin_nontemporal_load(&srcs[st + i]);
        uint4 a  = ybase[(size_t)sk * 2];
        uint4 bq = ybase[(size_t)sk * 2 + 1];
        acc[0]  += bf_lo(a.x);  acc[1]  += bf_hi(a.x);
        acc[2]  += bf_lo(a.y);  acc[3]  += bf_hi(a.y);
        acc[4]  += bf_lo(a.z);  acc[5]  += bf_hi(a.z);
        acc[6]  += bf_lo(a.w);  acc[7]  += bf_hi(a.w);
        acc[8]  += bf_lo(bq.x); acc[9]  += bf_hi(bq.x);
        acc[10] += bf_lo(bq.y); acc[11] += bf_hi(bq.y);
        acc[12] += bf_lo(bq.z); acc[13] += bf_hi(bq.z);
        acc[14] += bf_lo(bq.w); acc[15] += bf_hi(bq.w);
    }

    // reduce-scatter: lane j ends with cols 2j (v2[0]) and 2j+1 (v2[1])
    int hi4 = (j >> 2) & 1, hi2 = (j >> 1) & 1, hi1 = j & 1;
    float v8[8];
#pragma unroll
    for (int c = 0; c < 8; ++c) {
        float keep = hi4 ? acc[c + 8] : acc[c];
        float send = hi4 ? acc[c] : acc[c + 8];
        v8[c] = keep + __shfl_xor(send, 4, 8);
    }
    float v4[4];
#pragma unroll
    for (int c = 0; c < 4; ++c) {
        float keep = hi2 ? v8[c + 4] : v8[c];
        float send = hi2 ? v8[c] : v8[c + 4];
        v4[c] = keep + __shfl_xor(send, 2, 8);
    }
    float v2[2];
#pragma unroll
    for (int c = 0; c < 2; ++c) {
        float keep = hi1 ? v4[c + 2] : v4[c];
        float send = hi1 ? v4[c] : v4[c + 2];
        v2[c] = keep + __shfl_xor(send, 1, 8);
    }

    float ddv = dis[d];
    float2 b = ((const float2*)b1)[slice * 8 + j];
    float h0 = fmaxf(fmaf(v2[0], ddv, b.x), 0.0f);
    float h1 = fmaxf(fmaf(v2[1], ddv, b.y), 0.0f);

    // W2 rows loaded here (epilogue) to keep main-loop VGPR low
    const float* wr0 = W2 + (size_t)(slice * 16 + 2 * j) * 8;
    float p[8];
#pragma unroll
    for (int c = 0; c < 8; ++c) p[c] = h0 * wr0[c] + h1 * wr0[8 + c];
    float q4[4];
#pragma unroll
    for (int c = 0; c < 4; ++c) {
        float keep = hi4 ? p[c + 4] : p[c];
        float send = hi4 ? p[c] : p[c + 4];
        q4[c] = keep + __shfl_xor(send, 4, 8);
    }
    float q2[2];
#pragma unroll
    for (int c = 0; c < 2; ++c) {
        float keep = hi2 ? q4[c + 2] : q4[c];
        float send = hi2 ? q4[c] : q4[c + 2];
        q2[c] = keep + __shfl_xor(send, 2, 8);
    }
    float keep = hi1 ? q2[1] : q2[0];
    float send = hi1 ? q2[0] : q2[1];
    float q = keep + __shfl_xor(send, 1, 8);   // class j

    atomicAdd(&y2[(size_t)d * 8 + j], q * ddv);
}

// ---------- Aggregation 2 + bias + log_softmax -> out ------------------------
__global__ __launch_bounds__(256) void k_agg2(const float* __restrict__ y2,
                                              const int* __restrict__ srcs,
                                              const int* __restrict__ offs,
                                              const int* __restrict__ count,
                                              const float* __restrict__ dis,
                                              const float* __restrict__ b2,
                                              float* __restrict__ out) {
    int g = (blockIdx.x * 256 + threadIdx.x) >> 3;   // node
    int c = threadIdx.x & 7;                         // class
    if (g >= N_NODES) return;
    float acc = y2[(size_t)g * 8 + c];               // self-loop term
    float acc2 = 0.0f;
    int st = offs[g], n = count[g];
    int i = 0;
    for (; i + 2 <= n; i += 2) {
        int s0 = __builtin_nontemporal_load(&srcs[st + i]);
        int s1 = __builtin_nontemporal_load(&srcs[st + i + 1]);
        acc  += y2[(size_t)s0 * 8 + c];
        acc2 += y2[(size_t)s1 * 8 + c];
    }
    if (i < n) acc += y2[(size_t)__builtin_nontemporal_load(&srcs[st + i]) * 8 + c];
    acc += acc2;

    float o = fmaf(acc, dis[g], b2[c]);
    float m = o;
#pragma unroll
    for (int k = 1; k < 8; k <<= 1) m = fmaxf(m, __shfl_xor(m, k, 64));
    float e = expf(o - m);
    float ssum = e;
#pragma unroll
    for (int k = 1; k < 8; k <<= 1) ssum += __shfl_xor(ssum, k, 64);
    out[(size_t)g * 8 + c] = (o - m) - logf(ssum);
}

// ---------- host launcher -----------------------------------------------------
extern "C" void kernel_launch(void* const* d_in, const int* in_sizes, int n_in,
                              void* d_out, int out_size, void* d_ws, size_t ws_size,
                              hipStream_t stream) {
    const float* x  = (const float*)d_in[0];
    const int*   ei = (const int*)d_in[1];
    const float* W1 = (const float*)d_in[2];
    const float* b1 = (const float*)d_in[3];
    const float* W2 = (const float*)d_in[4];
    const float* b2 = (const float*)d_in[5];
    float* out = (float*)d_out;
    const int E = in_sizes[1] / 2;     // logical edge count
    const int PB = (E + EPB - 1) / EPB;
    const int Epad = (E + 3) & ~3;
    int slabInts = (PB * NBKT + 3) & ~3;

    // workspace layout (all 16B-aligned)
    int*   slab       = (int*)d_ws;                      // PB*NBKT ints
    int*   bkt_cnt    = slab + slabInts;                 // 784 ints
    int*   bkt_off    = bkt_cnt + 784;                   // 784 ints
    int*   bkt_cursor = bkt_off + 784;                   // 784 ints
    int*   count      = bkt_cursor + 784;                // N ints
    int*   offs       = count + N_NODES;                 // N ints
    float* dis        = (float*)(offs + N_NODES);        // N floats
    uint*  bkt_data   = (uint*)(dis + N_NODES);          // Epad uints
    int*   srcs       = (int*)(bkt_data + Epad);         // Epad ints
    uint*  y1s        = (uint*)(srcs + Epad);            // 8 slices * N*8 uints
    float* y2         = (float*)(y1s + (size_t)8 * SL_STRIDE);  // N*8 floats

    kA1    <<<PB, 256, 0, stream>>>(ei, E, slab);
    kA2    <<<1, 1024, 0, stream>>>(slab, PB, bkt_cnt, bkt_off, bkt_cursor);
    kA3    <<<PB, 256, 0, stream>>>(ei, E, bkt_cursor, bkt_data);
    kB     <<<NBKT, 256, 0, stream>>>(bkt_data, bkt_off, bkt_cnt, srcs, count, offs, dis, y2);

    k_gemm1<<<(N_NODES + 63) / 64, 256, 0, stream>>>(x, W1, dis, y1s);
    k_agg1s<<<8 * 3125, 256, 0, stream>>>(y1s, srcs, offs, count, dis, b1, W2, y2);
    k_agg2 <<<(N_NODES + 31) / 32, 256, 0, stream>>>(y2, srcs, offs, count, dis, b2, out);
}

// Round 10
// 247.774 us; speedup vs baseline: 1.1393x; 1.1393x over previous
//
#include <hip/hip_runtime.h>

#define N_NODES 100000
#define NBKT 782              // ceil(100000/128) buckets of 128 dst nodes
#define EPB 8192              // edges per partition block
#define SL_STRIDE 800000      // uints per y1 slice = N_NODES*8

typedef unsigned int uint;
typedef __attribute__((ext_vector_type(8))) short bf16x8;   // 8 bf16 (4 VGPRs)
typedef __attribute__((ext_vector_type(4))) float f32x4;    // MFMA acc

union FragU { uint4 u; bf16x8 b; };

// ---------- bf16 helpers ------------------------------------------------------
__device__ __forceinline__ uint pack_bf16_2(float a, float b) {
    uint ua = __float_as_uint(a), ub = __float_as_uint(b);
    ua += 0x7fff + ((ua >> 16) & 1);           // RNE
    ub += 0x7fff + ((ub >> 16) & 1);
    return (ua >> 16) | (ub & 0xffff0000u);
}
__device__ __forceinline__ float bf_lo(uint u) { return __uint_as_float(u << 16); }
__device__ __forceinline__ float bf_hi(uint u) { return __uint_as_float(u & 0xffff0000u); }

// ---------- edge-index access (handles int32 or raw int64 little-endian) ----
__device__ __forceinline__ int edge_at(const int* __restrict__ ei, int idx, int is64) {
    return is64 ? ei[2 * idx] : ei[idx];
}

// per-block dtype probe: 1 if int64 little-endian layout (all odd words zero)
__device__ __forceinline__ int block_probe_is64(const int* __restrict__ ei, int* sh) {
    int t = threadIdx.x;
    if (t == 0) *sh = 0;
    __syncthreads();
    int any = 0;
    for (int j = t; j < 4096; j += blockDim.x) any |= ei[2 * j + 1];
    if (any) atomicOr(sh, 1);
    __syncthreads();
    return (*sh == 0);
}

// ---------- phase A1: bucket histogram -> private slab (no global atomics) ---
__global__ __launch_bounds__(256) void kA1(const int* __restrict__ ei, int E,
                                           int* __restrict__ slab) {
    __shared__ int h[NBKT];
    __shared__ int shp;
    int t = threadIdx.x;
    int is64 = block_probe_is64(ei, &shp);
    for (int i = t; i < NBKT; i += 256) h[i] = 0;
    __syncthreads();
    int base = blockIdx.x * EPB;
    int end = min(base + EPB, E);
    for (int e = base + t; e < end; e += 256) {
        int d = edge_at(ei, E + e, is64);
        atomicAdd(&h[d >> 7], 1);
    }
    __syncthreads();
    for (int i = t; i < NBKT; i += 256)
        slab[(size_t)blockIdx.x * NBKT + i] = h[i];
}

// ---------- phase A2: reduce slabs + exclusive scan (1 block) ----------------
__global__ __launch_bounds__(1024) void kA2(const int* __restrict__ slab, int PB,
                                            int* __restrict__ bkt_cnt,
                                            int* __restrict__ bkt_off,
                                            int* __restrict__ bkt_cursor) {
    __shared__ int s[1024];
    int t = threadIdx.x;
    int v = 0;
    if (t < NBKT)
        for (int b = 0; b < PB; ++b) v += slab[(size_t)b * NBKT + t];
    if (t < NBKT) bkt_cnt[t] = v;
    s[t] = v;
    __syncthreads();
    for (int d = 1; d < 1024; d <<= 1) {
        int y = (t >= d) ? s[t - d] : 0;
        __syncthreads();
        s[t] += y;
        __syncthreads();
    }
    if (t < NBKT) {
        int o = s[t] - v;                      // exclusive
        bkt_off[t] = o;
        bkt_cursor[t] = o;
    }
}

// ---------- phase A3: partition edges into bucket-major records --------------
__global__ __launch_bounds__(256) void kA3(const int* __restrict__ ei, int E,
                                           int* __restrict__ bkt_cursor,
                                           uint* __restrict__ bkt_data) {
    __shared__ int h[NBKT];
    __shared__ int base[NBKT];
    __shared__ int shp;
    int t = threadIdx.x;
    int is64 = block_probe_is64(ei, &shp);
    for (int i = t; i < NBKT; i += 256) h[i] = 0;
    __syncthreads();
    int lo = blockIdx.x * EPB;
    int end = min(lo + EPB, E);
    for (int e = lo + t; e < end; e += 256) {
        int d = edge_at(ei, E + e, is64);
        atomicAdd(&h[d >> 7], 1);
    }
    __syncthreads();
    for (int i = t; i < NBKT; i += 256) {
        int c = h[i];
        base[i] = c ? atomicAdd(&bkt_cursor[i], c) : 0;
    }
    __syncthreads();
    for (int i = t; i < NBKT; i += 256) h[i] = 0;   // reuse as local rank cursor
    __syncthreads();
    for (int e = lo + t; e < end; e += 256) {
        int d = edge_at(ei, E + e, is64);
        int s = edge_at(ei, e, is64);
        int b = d >> 7;
        int r = atomicAdd(&h[b], 1);
        bkt_data[base[b] + r] = ((uint)s << 7) | (uint)(d & 127);
    }
}

// ---------- phase B: per-bucket CSR build + degrees + dis + y2 zero ----------
__global__ __launch_bounds__(256) void kB(const uint* __restrict__ bkt_data,
                                          const int* __restrict__ bkt_off,
                                          const int* __restrict__ bkt_cnt,
                                          int* __restrict__ srcs,
                                          int* __restrict__ count,
                                          int* __restrict__ offs,
                                          float* __restrict__ dis,
                                          float* __restrict__ y2) {
    __shared__ int lc[128];    // local degree
    __shared__ int sc[128];    // inclusive scan
    __shared__ int lcur[128];  // local fill cursor
    int t = threadIdx.x;
    int b = blockIdx.x;
    // zero this block's slice of y2 (800000 floats over 782 blocks)
    {
        int zb = b * 1024;
        int ze = min(zb + 1024, N_NODES * 8);
        for (int i = zb + t; i < ze; i += 256) y2[i] = 0.0f;
    }
    if (t < 128) { lc[t] = 0; lcur[t] = 0; }
    __syncthreads();
    int start = bkt_off[b];
    int n = bkt_cnt[b];
    for (int i = t; i < n; i += 256)
        atomicAdd(&lc[bkt_data[start + i] & 127], 1);
    __syncthreads();
    if (t < 128) sc[t] = lc[t];
    __syncthreads();
    for (int d = 1; d < 128; d <<= 1) {
        int y = 0;
        if (t < 128 && t >= d) y = sc[t - d];
        __syncthreads();
        if (t < 128) sc[t] += y;
        __syncthreads();
    }
    if (t < 128) {
        int node = b * 128 + t;
        if (node < N_NODES) {
            int c = lc[t];
            count[node] = c;
            offs[node] = start + sc[t] - c;
            dis[node] = rsqrtf((float)c + 1.0f);
        }
    }
    __syncthreads();
    for (int i = t; i < n; i += 256) {
        uint rec = bkt_data[start + i];
        int dl = rec & 127;
        int r = atomicAdd(&lcur[dl], 1);
        srcs[start + (sc[dl] - lc[dl]) + r] = rec >> 7;
    }
}

// ---------- GEMM1 (MFMA bf16): y1s = bf16((x @ W1) * dis)  sliced layout -----
// Block = 64 rows, 4 waves x 16 rows. LDS: W1^T bf16, 16B-XOR swizzled.
// Plain loads/stores (NT regressed: evict-first breaks L3 hand-off, r9).
__global__ __launch_bounds__(256) void k_gemm1(const float* __restrict__ x,
                                               const float* __restrict__ W,
                                               const float* __restrict__ dis,
                                               uint* __restrict__ y1s) {
    __shared__ uint4 WtA[2048];               // 32 KB
    char* wt = (char*)WtA;
    int t = threadIdx.x;

    const float4* W4 = (const float4*)W;
#pragma unroll
    for (int ii = 0; ii < 4; ++ii) {
        int tile = t + 256 * ii;              // 1024 (nq,kq) 4x4 tiles
        int nq = tile >> 5, kq = tile & 31;
        float4 r0 = W4[(4 * kq + 0) * 32 + nq];
        float4 r1 = W4[(4 * kq + 1) * 32 + nq];
        float4 r2 = W4[(4 * kq + 2) * 32 + nq];
        float4 r3 = W4[(4 * kq + 3) * 32 + nq];
        const float* p0 = (const float*)&r0;
        const float* p1 = (const float*)&r1;
        const float* p2 = (const float*)&r2;
        const float* p3 = (const float*)&r3;
#pragma unroll
        for (int cc = 0; cc < 4; ++cc) {
            int n = 4 * nq + cc;
            uint2 v;
            v.x = pack_bf16_2(p0[cc], p1[cc]);
            v.y = pack_bf16_2(p2[cc], p3[cc]);
            *(uint2*)(wt + n * 256 + (((kq >> 1) ^ (n & 7)) << 4) + ((kq & 1) << 3)) = v;
        }
    }
    __syncthreads();

    int w = t >> 6, lane = t & 63;
    int m = lane & 15, kg = lane >> 4;
    int row0 = blockIdx.x * 64 + 16 * w;

    int arow = row0 + m;
    bool av = arow < N_NODES;
    const float4* xr = (const float4*)(x + (size_t)arow * 128);
    float4 z4 = make_float4(0.f, 0.f, 0.f, 0.f);
    FragU af[4];
#pragma unroll
    for (int kf = 0; kf < 4; ++kf) {
        float4 g0 = av ? xr[8 * kf + 2 * kg]     : z4;
        float4 g1 = av ? xr[8 * kf + 2 * kg + 1] : z4;
        const float* a0 = (const float*)&g0;
        const float* a1 = (const float*)&g1;
        af[kf].u.x = pack_bf16_2(a0[0], a0[1]);
        af[kf].u.y = pack_bf16_2(a0[2], a0[3]);
        af[kf].u.z = pack_bf16_2(a1[0], a1[1]);
        af[kf].u.w = pack_bf16_2(a1[2], a1[3]);
    }

    int crow = row0 + 4 * kg;
    float dd[4];
#pragma unroll
    for (int rr = 0; rr < 4; ++rr)
        dd[rr] = (crow + rr < N_NODES) ? dis[crow + rr] : 0.0f;

#pragma unroll
    for (int ct = 0; ct < 8; ++ct) {          // col-tile == slice
        f32x4 acc = {0.f, 0.f, 0.f, 0.f};
#pragma unroll
        for (int kf = 0; kf < 4; ++kf) {
            int n = 16 * ct + m;              // B col = lane&15
            bf16x8 bw = *(const bf16x8*)(wt + n * 256 + ((((kf << 2) | kg) ^ (n & 7)) << 4));
            acc = __builtin_amdgcn_mfma_f32_16x16x32_bf16(af[kf].b, bw, acc, 0, 0, 0);
        }
#pragma unroll
        for (int rr = 0; rr < 4; ++rr) {
            float v = acc[rr] * dd[rr];
            float p = __shfl_xor(v, 1, 64);   // partner col (odd)
            if (!(lane & 1)) {
                int grow = crow + rr;
                if (grow < N_NODES)
                    y1s[(size_t)ct * SL_STRIDE + grow * 8 + (m >> 1)] = pack_bf16_2(v, p);
            }
        }
    }
}

// ---------- Aggregation 1 (sliced, XCD-local) fused with partial GEMM2 -------
// slice = blockIdx.x % 8 (round-robin XCD binding). 8-lane group per node.
// EDGE-PER-LANE: lane j handles edges i = j, j+8, ...; 2x dwordx4 per edge.
// Self-loop = virtual edge i==n. (r6 config: 32 VGPR, 99.4 us — do not unroll
// deeper [r7: +8 VGPR cost occupancy], do not NT [r9: L2/L3 evict-first].)
__global__ __launch_bounds__(256) void k_agg1s(const uint* __restrict__ y1s,
                                               const int* __restrict__ srcs,
                                               const int* __restrict__ offs,
                                               const int* __restrict__ count,
                                               const float* __restrict__ dis,
                                               const float* __restrict__ b1,
                                               const float* __restrict__ W2,
                                               float* __restrict__ y2) {
    int t = threadIdx.x;
    int slice = blockIdx.x & 7;
    int nb = blockIdx.x >> 3;
    int g = t >> 3;                    // group 0..31
    int j = t & 7;                     // lane in group
    int d = nb * 32 + g;               // node (3125*32 == 100000)

    // W2 rows for this lane (fixed): rows slice*16+2j, slice*16+2j+1
    float w0[8], w1[8];
    const float* wr0 = W2 + (size_t)(slice * 16 + 2 * j) * 8;
#pragma unroll
    for (int c = 0; c < 8; ++c) { w0[c] = wr0[c]; w1[c] = wr0[8 + c]; }

    const uint4* ybase = (const uint4*)(y1s + (size_t)slice * SL_STRIDE);
    float acc[16];
#pragma unroll
    for (int c = 0; c < 16; ++c) acc[c] = 0.0f;

    int st = offs[d], n = count[d];
    for (int i = j; i <= n; i += 8) {            // i==n -> self-loop (one lane)
        int sk = d;
        if (i < n) sk = srcs[st + i];
        uint4 a  = ybase[(size_t)sk * 2];
        uint4 bq = ybase[(size_t)sk * 2 + 1];
        acc[0]  += bf_lo(a.x);  acc[1]  += bf_hi(a.x);
        acc[2]  += bf_lo(a.y);  acc[3]  += bf_hi(a.y);
        acc[4]  += bf_lo(a.z);  acc[5]  += bf_hi(a.z);
        acc[6]  += bf_lo(a.w);  acc[7]  += bf_hi(a.w);
        acc[8]  += bf_lo(bq.x); acc[9]  += bf_hi(bq.x);
        acc[10] += bf_lo(bq.y); acc[11] += bf_hi(bq.y);
        acc[12] += bf_lo(bq.z); acc[13] += bf_hi(bq.z);
        acc[14] += bf_lo(bq.w); acc[15] += bf_hi(bq.w);
    }

    // reduce-scatter: lane j ends with cols 2j (v2[0]) and 2j+1 (v2[1])
    int hi4 = (j >> 2) & 1, hi2 = (j >> 1) & 1, hi1 = j & 1;
    float v8[8];
#pragma unroll
    for (int c = 0; c < 8; ++c) {
        float keep = hi4 ? acc[c + 8] : acc[c];
        float send = hi4 ? acc[c] : acc[c + 8];
        v8[c] = keep + __shfl_xor(send, 4, 8);
    }
    float v4[4];
#pragma unroll
    for (int c = 0; c < 4; ++c) {
        float keep = hi2 ? v8[c + 4] : v8[c];
        float send = hi2 ? v8[c] : v8[c + 4];
        v4[c] = keep + __shfl_xor(send, 2, 8);
    }
    float v2[2];
#pragma unroll
    for (int c = 0; c < 2; ++c) {
        float keep = hi1 ? v4[c + 2] : v4[c];
        float send = hi1 ? v4[c] : v4[c + 2];
        v2[c] = keep + __shfl_xor(send, 1, 8);
    }

    float ddv = dis[d];
    float2 b = ((const float2*)b1)[slice * 8 + j];
    float h0 = fmaxf(fmaf(v2[0], ddv, b.x), 0.0f);
    float h1 = fmaxf(fmaf(v2[1], ddv, b.y), 0.0f);

    float p[8];
#pragma unroll
    for (int c = 0; c < 8; ++c) p[c] = h0 * w0[c] + h1 * w1[c];
    float q4[4];
#pragma unroll
    for (int c = 0; c < 4; ++c) {
        float keep = hi4 ? p[c + 4] : p[c];
        float send = hi4 ? p[c] : p[c + 4];
        q4[c] = keep + __shfl_xor(send, 4, 8);
    }
    float q2[2];
#pragma unroll
    for (int c = 0; c < 2; ++c) {
        float keep = hi2 ? q4[c + 2] : q4[c];
        float send = hi2 ? q4[c] : q4[c + 2];
        q2[c] = keep + __shfl_xor(send, 2, 8);
    }
    float keep = hi1 ? q2[1] : q2[0];
    float send = hi1 ? q2[0] : q2[1];
    float q = keep + __shfl_xor(send, 1, 8);   // class j

    atomicAdd(&y2[(size_t)d * 8 + j], q * ddv);
}

// ---------- Aggregation 2 + bias + log_softmax -> out ------------------------
__global__ __launch_bounds__(256) void k_agg2(const float* __restrict__ y2,
                                              const int* __restrict__ srcs,
                                              const int* __restrict__ offs,
                                              const int* __restrict__ count,
                                              const float* __restrict__ dis,
                                              const float* __restrict__ b2,
                                              float* __restrict__ out) {
    int g = (blockIdx.x * 256 + threadIdx.x) >> 3;   // node
    int c = threadIdx.x & 7;                         // class
    if (g >= N_NODES) return;
    float acc = y2[(size_t)g * 8 + c];               // self-loop term
    float acc2 = 0.0f;
    int st = offs[g], n = count[g];
    int i = 0;
    for (; i + 2 <= n; i += 2) {
        int s0 = srcs[st + i], s1 = srcs[st + i + 1];
        acc  += y2[(size_t)s0 * 8 + c];
        acc2 += y2[(size_t)s1 * 8 + c];
    }
    if (i < n) acc += y2[(size_t)srcs[st + i] * 8 + c];
    acc += acc2;

    float o = fmaf(acc, dis[g], b2[c]);
    float m = o;
#pragma unroll
    for (int k = 1; k < 8; k <<= 1) m = fmaxf(m, __shfl_xor(m, k, 64));
    float e = expf(o - m);
    float ssum = e;
#pragma unroll
    for (int k = 1; k < 8; k <<= 1) ssum += __shfl_xor(ssum, k, 64);
    out[(size_t)g * 8 + c] = (o - m) - logf(ssum);
}

// ---------- host launcher -----------------------------------------------------
extern "C" void kernel_launch(void* const* d_in, const int* in_sizes, int n_in,
                              void* d_out, int out_size, void* d_ws, size_t ws_size,
                              hipStream_t stream) {
    const float* x  = (const float*)d_in[0];
    const int*   ei = (const int*)d_in[1];
    const float* W1 = (const float*)d_in[2];
    const float* b1 = (const float*)d_in[3];
    const float* W2 = (const float*)d_in[4];
    const float* b2 = (const float*)d_in[5];
    float* out = (float*)d_out;
    const int E = in_sizes[1] / 2;     // logical edge count
    const int PB = (E + EPB - 1) / EPB;
    const int Epad = (E + 3) & ~3;
    int slabInts = (PB * NBKT + 3) & ~3;

    // workspace layout (all 16B-aligned)
    int*   slab       = (int*)d_ws;                      // PB*NBKT ints
    int*   bkt_cnt    = slab + slabInts;                 // 784 ints
    int*   bkt_off    = bkt_cnt + 784;                   // 784 ints
    int*   bkt_cursor = bkt_off + 784;                   // 784 ints
    int*   count      = bkt_cursor + 784;                // N ints
    int*   offs       = count + N_NODES;                 // N ints
    float* dis        = (float*)(offs + N_NODES);        // N floats
    uint*  bkt_data   = (uint*)(dis + N_NODES);          // Epad uints
    int*   srcs       = (int*)(bkt_data + Epad);         // Epad ints
    uint*  y1s        = (uint*)(srcs + Epad);            // 8 slices * N*8 uints
    float* y2         = (float*)(y1s + (size_t)8 * SL_STRIDE);  // N*8 floats

    kA1    <<<PB, 256, 0, stream>>>(ei, E, slab);
    kA2    <<<1, 1024, 0, stream>>>(slab, PB, bkt_cnt, bkt_off, bkt_cursor);
    kA3    <<<PB, 256, 0, stream>>>(ei, E, bkt_cursor, bkt_data);
    kB     <<<NBKT, 256, 0, stream>>>(bkt_data, bkt_off, bkt_cnt, srcs, count, offs, dis, y2);

    k_gemm1<<<(N_NODES + 63) / 64, 256, 0, stream>>>(x, W1, dis, y1s);
    k_agg1s<<<8 * 3125, 256, 0, stream>>>(y1s, srcs, offs, count, dis, b1, W2, y2);
    k_agg2 <<<(N_NODES + 31) / 32, 256, 0, stream>>>(y2, srcs, offs, count, dis, b2, out);
}

// Round 11
// 222.192 us; speedup vs baseline: 1.2705x; 1.1151x over previous
//
#include <hip/hip_runtime.h>

#define N_NODES 100000
#define NBKT 782              // ceil(100000/128) buckets of 128 dst nodes
#define EPB 8192              // edges per partition block
#define SL_STRIDE 800000      // uints per y1 slice = N_NODES*8

typedef unsigned int uint;
typedef __attribute__((ext_vector_type(8))) short bf16x8;   // 8 bf16 (4 VGPRs)
typedef __attribute__((ext_vector_type(4))) float f32x4;    // MFMA acc

union FragU { uint4 u; bf16x8 b; };

// ---------- bf16 helpers ------------------------------------------------------
__device__ __forceinline__ uint pack_bf16_2(float a, float b) {
    uint ua = __float_as_uint(a), ub = __float_as_uint(b);
    ua += 0x7fff + ((ua >> 16) & 1);           // RNE
    ub += 0x7fff + ((ub >> 16) & 1);
    return (ua >> 16) | (ub & 0xffff0000u);
}
__device__ __forceinline__ float bf_lo(uint u) { return __uint_as_float(u << 16); }
__device__ __forceinline__ float bf_hi(uint u) { return __uint_as_float(u & 0xffff0000u); }

// ---------- edge-index access (handles int32 or raw int64 little-endian) ----
__device__ __forceinline__ int edge_at(const int* __restrict__ ei, int idx, int is64) {
    return is64 ? ei[2 * idx] : ei[idx];
}

// per-block dtype probe: 1 if int64 little-endian layout (all odd words zero)
__device__ __forceinline__ int block_probe_is64(const int* __restrict__ ei, int* sh) {
    int t = threadIdx.x;
    if (t == 0) *sh = 0;
    __syncthreads();
    int any = 0;
    for (int j = t; j < 4096; j += blockDim.x) any |= ei[2 * j + 1];
    if (any) atomicOr(sh, 1);
    __syncthreads();
    return (*sh == 0);
}

// ---------- phase A1: bucket histogram -> private slab (no global atomics) ---
__global__ __launch_bounds__(256) void kA1(const int* __restrict__ ei, int E,
                                           int* __restrict__ slab) {
    __shared__ int h[NBKT];
    __shared__ int shp;
    int t = threadIdx.x;
    int is64 = block_probe_is64(ei, &shp);
    for (int i = t; i < NBKT; i += 256) h[i] = 0;
    __syncthreads();
    int base = blockIdx.x * EPB;
    int end = min(base + EPB, E);
    for (int e = base + t; e < end; e += 256) {
        int d = edge_at(ei, E + e, is64);
        atomicAdd(&h[d >> 7], 1);
    }
    __syncthreads();
    for (int i = t; i < NBKT; i += 256)
        slab[(size_t)blockIdx.x * NBKT + i] = h[i];
}

// ---------- phase A2a: grid-parallel slab reduce (one wave per bucket) -------
// (r10 lesson: single-block serial reduce of the 612KB slab cost ~28us —
//  one CU's miss-concurrency vs ~10k remote lines. Parallelize across CUs.)
__global__ __launch_bounds__(256) void kA2a(const int* __restrict__ slab, int PB,
                                            int* __restrict__ bkt_cnt) {
    int w = threadIdx.x >> 6;                 // wave in block (0..3)
    int l = threadIdx.x & 63;                 // lane
    int k = blockIdx.x * 4 + w;               // bucket
    if (k >= NBKT) return;
    int v = 0;
    for (int b = l; b < PB; b += 64)
        v += slab[(size_t)b * NBKT + k];
#pragma unroll
    for (int s = 32; s; s >>= 1) v += __shfl_xor(v, s, 64);
    if (l == 0) bkt_cnt[k] = v;
}

// ---------- phase A2b: exclusive scan of 782 bucket counts (1 block, LDS) ----
__global__ __launch_bounds__(1024) void kA2b(const int* __restrict__ bkt_cnt,
                                             int* __restrict__ bkt_off,
                                             int* __restrict__ bkt_cursor) {
    __shared__ int s[1024];
    int t = threadIdx.x;
    int v = (t < NBKT) ? bkt_cnt[t] : 0;
    s[t] = v;
    __syncthreads();
    for (int d = 1; d < 1024; d <<= 1) {
        int y = (t >= d) ? s[t - d] : 0;
        __syncthreads();
        s[t] += y;
        __syncthreads();
    }
    if (t < NBKT) {
        int o = s[t] - v;                      // exclusive
        bkt_off[t] = o;
        bkt_cursor[t] = o;
    }
}

// ---------- phase A3: partition edges into bucket-major records --------------
__global__ __launch_bounds__(256) void kA3(const int* __restrict__ ei, int E,
                                           int* __restrict__ bkt_cursor,
                                           uint* __restrict__ bkt_data) {
    __shared__ int h[NBKT];
    __shared__ int base[NBKT];
    __shared__ int shp;
    int t = threadIdx.x;
    int is64 = block_probe_is64(ei, &shp);
    for (int i = t; i < NBKT; i += 256) h[i] = 0;
    __syncthreads();
    int lo = blockIdx.x * EPB;
    int end = min(lo + EPB, E);
    for (int e = lo + t; e < end; e += 256) {
        int d = edge_at(ei, E + e, is64);
        atomicAdd(&h[d >> 7], 1);
    }
    __syncthreads();
    for (int i = t; i < NBKT; i += 256) {
        int c = h[i];
        base[i] = c ? atomicAdd(&bkt_cursor[i], c) : 0;
    }
    __syncthreads();
    for (int i = t; i < NBKT; i += 256) h[i] = 0;   // reuse as local rank cursor
    __syncthreads();
    for (int e = lo + t; e < end; e += 256) {
        int d = edge_at(ei, E + e, is64);
        int s = edge_at(ei, e, is64);
        int b = d >> 7;
        int r = atomicAdd(&h[b], 1);
        bkt_data[base[b] + r] = ((uint)s << 7) | (uint)(d & 127);
    }
}

// ---------- phase B: per-bucket CSR build + degrees + dis + y2 zero ----------
__global__ __launch_bounds__(256) void kB(const uint* __restrict__ bkt_data,
                                          const int* __restrict__ bkt_off,
                                          const int* __restrict__ bkt_cnt,
                                          int* __restrict__ srcs,
                                          int* __restrict__ count,
                                          int* __restrict__ offs,
                                          float* __restrict__ dis,
                                          float* __restrict__ y2) {
    __shared__ int lc[128];    // local degree
    __shared__ int sc[128];    // inclusive scan
    __shared__ int lcur[128];  // local fill cursor
    int t = threadIdx.x;
    int b = blockIdx.x;
    // zero this block's slice of y2 (800000 floats over 782 blocks)
    {
        int zb = b * 1024;
        int ze = min(zb + 1024, N_NODES * 8);
        for (int i = zb + t; i < ze; i += 256) y2[i] = 0.0f;
    }
    if (t < 128) { lc[t] = 0; lcur[t] = 0; }
    __syncthreads();
    int start = bkt_off[b];
    int n = bkt_cnt[b];
    for (int i = t; i < n; i += 256)
        atomicAdd(&lc[bkt_data[start + i] & 127], 1);
    __syncthreads();
    if (t < 128) sc[t] = lc[t];
    __syncthreads();
    for (int d = 1; d < 128; d <<= 1) {
        int y = 0;
        if (t < 128 && t >= d) y = sc[t - d];
        __syncthreads();
        if (t < 128) sc[t] += y;
        __syncthreads();
    }
    if (t < 128) {
        int node = b * 128 + t;
        if (node < N_NODES) {
            int c = lc[t];
            count[node] = c;
            offs[node] = start + sc[t] - c;
            dis[node] = rsqrtf((float)c + 1.0f);
        }
    }
    __syncthreads();
    for (int i = t; i < n; i += 256) {
        uint rec = bkt_data[start + i];
        int dl = rec & 127;
        int r = atomicAdd(&lcur[dl], 1);
        srcs[start + (sc[dl] - lc[dl]) + r] = rec >> 7;
    }
}

// ---------- GEMM1 (MFMA bf16): y1s = bf16((x @ W1) * dis)  sliced layout -----
// Block = 64 rows, 4 waves x 16 rows. LDS: W1^T bf16, 16B-XOR swizzled.
// Plain loads/stores (NT regressed: evict-first breaks L3 hand-off, r9).
__global__ __launch_bounds__(256) void k_gemm1(const float* __restrict__ x,
                                               const float* __restrict__ W,
                                               const float* __restrict__ dis,
                                               uint* __restrict__ y1s) {
    __shared__ uint4 WtA[2048];               // 32 KB
    char* wt = (char*)WtA;
    int t = threadIdx.x;

    const float4* W4 = (const float4*)W;
#pragma unroll
    for (int ii = 0; ii < 4; ++ii) {
        int tile = t + 256 * ii;              // 1024 (nq,kq) 4x4 tiles
        int nq = tile >> 5, kq = tile & 31;
        float4 r0 = W4[(4 * kq + 0) * 32 + nq];
        float4 r1 = W4[(4 * kq + 1) * 32 + nq];
        float4 r2 = W4[(4 * kq + 2) * 32 + nq];
        float4 r3 = W4[(4 * kq + 3) * 32 + nq];
        const float* p0 = (const float*)&r0;
        const float* p1 = (const float*)&r1;
        const float* p2 = (const float*)&r2;
        const float* p3 = (const float*)&r3;
#pragma unroll
        for (int cc = 0; cc < 4; ++cc) {
            int n = 4 * nq + cc;
            uint2 v;
            v.x = pack_bf16_2(p0[cc], p1[cc]);
            v.y = pack_bf16_2(p2[cc], p3[cc]);
            *(uint2*)(wt + n * 256 + (((kq >> 1) ^ (n & 7)) << 4) + ((kq & 1) << 3)) = v;
        }
    }
    __syncthreads();

    int w = t >> 6, lane = t & 63;
    int m = lane & 15, kg = lane >> 4;
    int row0 = blockIdx.x * 64 + 16 * w;

    int arow = row0 + m;
    bool av = arow < N_NODES;
    const float4* xr = (const float4*)(x + (size_t)arow * 128);
    float4 z4 = make_float4(0.f, 0.f, 0.f, 0.f);
    FragU af[4];
#pragma unroll
    for (int kf = 0; kf < 4; ++kf) {
        float4 g0 = av ? xr[8 * kf + 2 * kg]     : z4;
        float4 g1 = av ? xr[8 * kf + 2 * kg + 1] : z4;
        const float* a0 = (const float*)&g0;
        const float* a1 = (const float*)&g1;
        af[kf].u.x = pack_bf16_2(a0[0], a0[1]);
        af[kf].u.y = pack_bf16_2(a0[2], a0[3]);
        af[kf].u.z = pack_bf16_2(a1[0], a1[1]);
        af[kf].u.w = pack_bf16_2(a1[2], a1[3]);
    }

    int crow = row0 + 4 * kg;
    float dd[4];
#pragma unroll
    for (int rr = 0; rr < 4; ++rr)
        dd[rr] = (crow + rr < N_NODES) ? dis[crow + rr] : 0.0f;

#pragma unroll
    for (int ct = 0; ct < 8; ++ct) {          // col-tile == slice
        f32x4 acc = {0.f, 0.f, 0.f, 0.f};
#pragma unroll
        for (int kf = 0; kf < 4; ++kf) {
            int n = 16 * ct + m;              // B col = lane&15
            bf16x8 bw = *(const bf16x8*)(wt + n * 256 + ((((kf << 2) | kg) ^ (n & 7)) << 4));
            acc = __builtin_amdgcn_mfma_f32_16x16x32_bf16(af[kf].b, bw, acc, 0, 0, 0);
        }
#pragma unroll
        for (int rr = 0; rr < 4; ++rr) {
            float v = acc[rr] * dd[rr];
            float p = __shfl_xor(v, 1, 64);   // partner col (odd)
            if (!(lane & 1)) {
                int grow = crow + rr;
                if (grow < N_NODES)
                    y1s[(size_t)ct * SL_STRIDE + grow * 8 + (m >> 1)] = pack_bf16_2(v, p);
            }
        }
    }
}

// ---------- Aggregation 1 (sliced, XCD-local) fused with partial GEMM2 -------
// slice = blockIdx.x % 8 (round-robin XCD binding). 8-lane group per node.
// EDGE-PER-LANE: lane j handles edges i = j, j+8, ...; 2x dwordx4 per edge.
// Self-loop = virtual edge i==n. (r6 config: 32 VGPR, ~100 us — do not unroll
// deeper [r7: +8 VGPR cost occupancy], do not NT [r9: L2/L3 evict-first].)
__global__ __launch_bounds__(256) void k_agg1s(const uint* __restrict__ y1s,
                                               const int* __restrict__ srcs,
                                               const int* __restrict__ offs,
                                               const int* __restrict__ count,
                                               const float* __restrict__ dis,
                                               const float* __restrict__ b1,
                                               const float* __restrict__ W2,
                                               float* __restrict__ y2) {
    int t = threadIdx.x;
    int slice = blockIdx.x & 7;
    int nb = blockIdx.x >> 3;
    int g = t >> 3;                    // group 0..31
    int j = t & 7;                     // lane in group
    int d = nb * 32 + g;               // node (3125*32 == 100000)

    // W2 rows for this lane (fixed): rows slice*16+2j, slice*16+2j+1
    float w0[8], w1[8];
    const float* wr0 = W2 + (size_t)(slice * 16 + 2 * j) * 8;
#pragma unroll
    for (int c = 0; c < 8; ++c) { w0[c] = wr0[c]; w1[c] = wr0[8 + c]; }

    const uint4* ybase = (const uint4*)(y1s + (size_t)slice * SL_STRIDE);
    float acc[16];
#pragma unroll
    for (int c = 0; c < 16; ++c) acc[c] = 0.0f;

    int st = offs[d], n = count[d];
    for (int i = j; i <= n; i += 8) {            // i==n -> self-loop (one lane)
        int sk = d;
        if (i < n) sk = srcs[st + i];
        uint4 a  = ybase[(size_t)sk * 2];
        uint4 bq = ybase[(size_t)sk * 2 + 1];
        acc[0]  += bf_lo(a.x);  acc[1]  += bf_hi(a.x);
        acc[2]  += bf_lo(a.y);  acc[3]  += bf_hi(a.y);
        acc[4]  += bf_lo(a.z);  acc[5]  += bf_hi(a.z);
        acc[6]  += bf_lo(a.w);  acc[7]  += bf_hi(a.w);
        acc[8]  += bf_lo(bq.x); acc[9]  += bf_hi(bq.x);
        acc[10] += bf_lo(bq.y); acc[11] += bf_hi(bq.y);
        acc[12] += bf_lo(bq.z); acc[13] += bf_hi(bq.z);
        acc[14] += bf_lo(bq.w); acc[15] += bf_hi(bq.w);
    }

    // reduce-scatter: lane j ends with cols 2j (v2[0]) and 2j+1 (v2[1])
    int hi4 = (j >> 2) & 1, hi2 = (j >> 1) & 1, hi1 = j & 1;
    float v8[8];
#pragma unroll
    for (int c = 0; c < 8; ++c) {
        float keep = hi4 ? acc[c + 8] : acc[c];
        float send = hi4 ? acc[c] : acc[c + 8];
        v8[c] = keep + __shfl_xor(send, 4, 8);
    }
    float v4[4];
#pragma unroll
    for (int c = 0; c < 4; ++c) {
        float keep = hi2 ? v8[c + 4] : v8[c];
        float send = hi2 ? v8[c] : v8[c + 4];
        v4[c] = keep + __shfl_xor(send, 2, 8);
    }
    float v2[2];
#pragma unroll
    for (int c = 0; c < 2; ++c) {
        float keep = hi1 ? v4[c + 2] : v4[c];
        float send = hi1 ? v4[c] : v4[c + 2];
        v2[c] = keep + __shfl_xor(send, 1, 8);
    }

    float ddv = dis[d];
    float2 b = ((const float2*)b1)[slice * 8 + j];
    float h0 = fmaxf(fmaf(v2[0], ddv, b.x), 0.0f);
    float h1 = fmaxf(fmaf(v2[1], ddv, b.y), 0.0f);

    float p[8];
#pragma unroll
    for (int c = 0; c < 8; ++c) p[c] = h0 * w0[c] + h1 * w1[c];
    float q4[4];
#pragma unroll
    for (int c = 0; c < 4; ++c) {
        float keep = hi4 ? p[c + 4] : p[c];
        float send = hi4 ? p[c] : p[c + 4];
        q4[c] = keep + __shfl_xor(send, 4, 8);
    }
    float q2[2];
#pragma unroll
    for (int c = 0; c < 2; ++c) {
        float keep = hi2 ? q4[c + 2] : q4[c];
        float send = hi2 ? q4[c] : q4[c + 2];
        q2[c] = keep + __shfl_xor(send, 2, 8);
    }
    float keep = hi1 ? q2[1] : q2[0];
    float send = hi1 ? q2[0] : q2[1];
    float q = keep + __shfl_xor(send, 1, 8);   // class j

    atomicAdd(&y2[(size_t)d * 8 + j], q * ddv);
}

// ---------- Aggregation 2 + bias + log_softmax -> out ------------------------
__global__ __launch_bounds__(256) void k_agg2(const float* __restrict__ y2,
                                              const int* __restrict__ srcs,
                                              const int* __restrict__ offs,
                                              const int* __restrict__ count,
                                              const float* __restrict__ dis,
                                              const float* __restrict__ b2,
                                              float* __restrict__ out) {
    int g = (blockIdx.x * 256 + threadIdx.x) >> 3;   // node
    int c = threadIdx.x & 7;                         // class
    if (g >= N_NODES) return;
    float acc = y2[(size_t)g * 8 + c];               // self-loop term
    float acc2 = 0.0f;
    int st = offs[g], n = count[g];
    int i = 0;
    for (; i + 2 <= n; i += 2) {
        int s0 = srcs[st + i], s1 = srcs[st + i + 1];
        acc  += y2[(size_t)s0 * 8 + c];
        acc2 += y2[(size_t)s1 * 8 + c];
    }
    if (i < n) acc += y2[(size_t)srcs[st + i] * 8 + c];
    acc += acc2;

    float o = fmaf(acc, dis[g], b2[c]);
    float m = o;
#pragma unroll
    for (int k = 1; k < 8; k <<= 1) m = fmaxf(m, __shfl_xor(m, k, 64));
    float e = expf(o - m);
    float ssum = e;
#pragma unroll
    for (int k = 1; k < 8; k <<= 1) ssum += __shfl_xor(ssum, k, 64);
    out[(size_t)g * 8 + c] = (o - m) - logf(ssum);
}

// ---------- host launcher -----------------------------------------------------
extern "C" void kernel_launch(void* const* d_in, const int* in_sizes, int n_in,
                              void* d_out, int out_size, void* d_ws, size_t ws_size,
                              hipStream_t stream) {
    const float* x  = (const float*)d_in[0];
    const int*   ei = (const int*)d_in[1];
    const float* W1 = (const float*)d_in[2];
    const float* b1 = (const float*)d_in[3];
    const float* W2 = (const float*)d_in[4];
    const float* b2 = (const float*)d_in[5];
    float* out = (float*)d_out;
    const int E = in_sizes[1] / 2;     // logical edge count
    const int PB = (E + EPB - 1) / EPB;
    const int Epad = (E + 3) & ~3;
    int slabInts = (PB * NBKT + 3) & ~3;

    // workspace layout (all 16B-aligned)
    int*   slab       = (int*)d_ws;                      // PB*NBKT ints
    int*   bkt_cnt    = slab + slabInts;                 // 784 ints
    int*   bkt_off    = bkt_cnt + 784;                   // 784 ints
    int*   bkt_cursor = bkt_off + 784;                   // 784 ints
    int*   count      = bkt_cursor + 784;                // N ints
    int*   offs       = count + N_NODES;                 // N ints
    float* dis        = (float*)(offs + N_NODES);        // N floats
    uint*  bkt_data   = (uint*)(dis + N_NODES);          // Epad uints
    int*   srcs       = (int*)(bkt_data + Epad);         // Epad ints
    uint*  y1s        = (uint*)(srcs + Epad);            // 8 slices * N*8 uints
    float* y2         = (float*)(y1s + (size_t)8 * SL_STRIDE);  // N*8 floats

    kA1    <<<PB, 256, 0, stream>>>(ei, E, slab);
    kA2a   <<<(NBKT + 3) / 4, 256, 0, stream>>>(slab, PB, bkt_cnt);
    kA2b   <<<1, 1024, 0, stream>>>(bkt_cnt, bkt_off, bkt_cursor);
    kA3    <<<PB, 256, 0, stream>>>(ei, E, bkt_cursor, bkt_data);
    kB     <<<NBKT, 256, 0, stream>>>(bkt_data, bkt_off, bkt_cnt, srcs, count, offs, dis, y2);

    k_gemm1<<<(N_NODES + 63) / 64, 256, 0, stream>>>(x, W1, dis, y1s);
    k_agg1s<<<8 * 3125, 256, 0, stream>>>(y1s, srcs, offs, count, dis, b1, W2, y2);
    k_agg2 <<<(N_NODES + 31) / 32, 256, 0, stream>>>(y2, srcs, offs, count, dis, b2, out);
}